// Round 14
// baseline (33.552 us; speedup 1.0000x reference)
//
#include <hip/hip_runtime.h>
#include <math.h>

#define N_PART 50000
#define KMAX 80
#define KS 4
#define LPP 8    // lanes per particle, slot stride = 8; <=10 trips/lane

typedef __attribute__((ext_vector_type(8))) _Float16 h8;
typedef __attribute__((ext_vector_type(2))) _Float16 h2;

// minimax odd polynomial for atan(t), t in [-1,1]; max abs err ~1e-5
__device__ __forceinline__ float atan_poly(float t) {
    float t2 = t * t;
    float p = -0.01172120f;
    p = p * t2 + 0.05265332f;
    p = p * t2 - 0.11643287f;
    p = p * t2 + 0.19354346f;
    p = p * t2 - 0.33262347f;
    p = p * t2 + 0.99997726f;
    return t * p;
}

struct PV { float px, py, pz, ux, uy, uz; };

__device__ __forceinline__ void load_pv(const float* __restrict__ pos,
                                        const float* __restrict__ vel,
                                        int i, PV& v) {
    v.px = pos[3*i];  v.py = pos[3*i+1];  v.pz = pos[3*i+2];
    v.ux = vel[3*i];  v.uy = vel[3*i+1];  v.uz = vel[3*i+2];
}

// One (always-valid) pair's contribution: transform + corner fold.
// W layout: 16 halves per corner (32B): [0..8]=W values fp16, [9..15]=0.
__device__ __forceinline__ void pair_contrib(
    const PV& n, float cpx, float cpy, float cpz,
    const _Float16* __restrict__ WsHP,
    float& acc0, float& acc1, float& acc2)
{
    const float inv_r = 1.0f / 0.3f;
    const float eps   = 1e-12f;
    const float FOUR_OVER_PI = 1.27323954473516268615f;

    float rx = (n.px - cpx) * inv_r;
    float ry = (n.py - cpy) * inv_r;
    float rz = (n.pz - cpz) * inv_r;

    float sq = rx * rx + ry * ry + rz * rz;

    // window_poly6: valid pairs have sq < 1, so no upper clamp needed
    float t1  = 1.0f - sq;
    float imp = fmaxf(t1 * t1 * t1, 0.0f);

    // ---- ball -> cylinder (volume preserving), branch-lite ----
    float norm  = sqrtf(fmaxf(sq, eps));
    float sq_xy = rx * rx + ry * ry;
    bool  top   = (1.25f * rz * rz) > sq_xy;
    float z1    = top ? copysignf(norm, rz) : 1.5f * rz;

    // ---- cylinder -> cube ----
    // x1,y1 are never needed: xb/num/den use raw rx,ry (common positive scale),
    // and nxy_top = sqrt(sq_xy)*s_top = sqrt(sq_xy*3*norm/(norm+|rz|)).
    float nxy = top ? sqrtf(sq_xy * 3.0f * norm * __builtin_amdgcn_rcpf(norm + fabsf(rz)))
                    : norm;
    bool  xb  = fabsf(ry) <= fabsf(rx);
    float num = xb ? ry : rx;
    float den = xb ? rx : ry;
    float sden = (fabsf(den) > eps) ? den : 1.0f;
    float t    = num * __builtin_amdgcn_rcpf(sden);
    float at   = atan_poly(t);
    float sd   = copysignf(nxy, den);
    float u    = sd * FOUR_OVER_PI * at;
    float x2   = xb ? sd : u;
    float y2   = xb ? u  : sd;

    // ---- trilinear grid coords, align_corners=True, clamped ----
    // t >= 0 so cvt_i32 (trunc) == floor; fract gives t - floor(t) in 1 inst.
    float tx = fminf(fmaxf(x2 * 1.5f + 1.5f, 0.0f), 3.0f);
    float ty = fminf(fmaxf(y2 * 1.5f + 1.5f, 0.0f), 3.0f);
    float tz = fminf(fmaxf(z1 * 1.5f + 1.5f, 0.0f), 3.0f);
    int xi0 = (int)tx, yi0 = (int)ty, zi0 = (int)tz;
    float wx1 = __builtin_amdgcn_fractf(tx);
    float wy1 = __builtin_amdgcn_fractf(ty);
    float wz1 = __builtin_amdgcn_fractf(tz);
    int xi1 = min(xi0 + 1, KS - 1);
    int yi1 = min(yi0 + 1, KS - 1);
    int zi1 = min(zi0 + 1, KS - 1);
    float wx0 = 1.0f - wx1, wy0 = 1.0f - wy1, wz0 = 1.0f - wz1;

    int   zia[2] = { zi0 << 4, zi1 << 4 };  float wza[2] = { wz0, wz1 };
    int   yia[2] = { yi0 << 2, yi1 << 2 };  float wya[2] = { wy0, wy1 };
    int   xia[2] = { xi0, xi1 };            float wxa[2] = { wx0, wx1 };

    // ---- per-pair M = sum_c w_c * W_c, accumulated in packed fp16 ----
    h2 M01 = (h2)(_Float16)0.0f;
    h2 M23 = (h2)(_Float16)0.0f;
    h2 M45 = (h2)(_Float16)0.0f;
    h2 M67 = (h2)(_Float16)0.0f;
    h2 M89 = (h2)(_Float16)0.0f;   // [0] = W[2][2] accum, [1] = 0

    #pragma unroll
    for (int cz = 0; cz < 2; ++cz) {
        #pragma unroll
        for (int cy = 0; cy < 2; ++cy) {
            float wzy = wza[cz] * wya[cy];
            int   czy = zia[cz] + yia[cy];
            #pragma unroll
            for (int cx = 0; cx < 2; ++cx) {
                int corner = czy + xia[cx];
                const _Float16* Wc = &WsHP[corner << 4];
                h8 lo = *(const h8*)Wc;          // ds_read_b128
                h2 hi = *(const h2*)(Wc + 8);    // ds_read_b32, same addr +16
                float wf = wzy * wxa[cx];
                _Float16 wh = (_Float16)wf;
                h2 ww = { wh, wh };
                M01 += ww * __builtin_shufflevector(lo, lo, 0, 1);
                M23 += ww * __builtin_shufflevector(lo, lo, 2, 3);
                M45 += ww * __builtin_shufflevector(lo, lo, 4, 5);
                M67 += ww * __builtin_shufflevector(lo, lo, 6, 7);
                M89 += ww * hi;
            }
        }
    }

    float m0 = (float)M01[0], m1 = (float)M01[1];
    float m2 = (float)M23[0], m3 = (float)M23[1];
    float m4 = (float)M45[0], m5 = (float)M45[1];
    float m6 = (float)M67[0], m7 = (float)M67[1];
    float m8 = (float)M89[0];
    float s0 = n.ux * m0 + n.uy * m3 + n.uz * m6;
    float s1 = n.ux * m1 + n.uy * m4 + n.uz * m7;
    float s2 = n.ux * m2 + n.uy * m5 + n.uz * m8;
    acc0 += imp * s0;
    acc1 += imp * s1;
    acc2 += imp * s2;
}

__global__ __launch_bounds__(256) void cconv_kernel(
    const float* __restrict__ pos,
    const float* __restrict__ vel,
    const float* __restrict__ Wg,      // [64*3*3] (g, cin, cout)
    const int* __restrict__ nidx,      // [N][KMAX]
    const void* __restrict__ nmask,    // [N][KMAX], dtype detected per-wave
    float* __restrict__ out)           // [N][3]
{
    // 16 halves (32B) per corner: [0..8] = W, rest 0. 2KB total.
    __shared__ _Float16 WsHP[64 * 16];
    for (int t = threadIdx.x; t < 64 * 16; t += blockDim.x) {
        int g = t >> 4, r = t & 15;
        WsHP[t] = (r < 9) ? (_Float16)Wg[g * 9 + r] : (_Float16)0.0f;
    }
    __syncthreads();

    int gid = blockIdx.x * blockDim.x + threadIdx.x;
    int p   = gid >> 3;        // 8 lanes per particle
    int sub = gid & 7;
    if (p >= N_PART) return;

    const int base = p * KMAX;

    // ---- per-wave mask-dtype detection (int32 vs byte-bool storage) ----
    bool byteMask;
    {
        const unsigned* mw = (const unsigned*)nmask;
        int lane = threadIdx.x & 63;
        bool big = false;
        #pragma unroll
        for (int i = 0; i < 8; ++i)
            big |= (mw[lane + 64 * i] > 1u);
        byteMask = (__ballot(big) != 0ULL);
    }

    float cpx = pos[3 * p], cpy = pos[3 * p + 1], cpz = pos[3 * p + 2];

    // ---- neighbor count: mask is a prefix, so count = sum of nonzeros ----
    // 8 lanes x 10 slots (sub + 8m) cover 0..79 exactly.
    int lc = 0;
    if (byteMask) {
        const unsigned char* mb = (const unsigned char*)nmask;
        #pragma unroll
        for (int m = 0; m < 10; ++m) lc += (mb[base + sub + (m << 3)] != 0);
    } else {
        const int* mi = (const int*)nmask;
        #pragma unroll
        for (int m = 0; m < 10; ++m) lc += (mi[base + sub + (m << 3)] != 0);
    }
    lc += __shfl_xor(lc, 1); lc += __shfl_xor(lc, 2); lc += __shfl_xor(lc, 4);
    const int cnt = lc;

    // ---- 2-deep rolling pipeline: nidx 2 trips ahead, PV 1 trip ahead ----
    int idxA = nidx[base + sub];            // trip 0
    int idxB = nidx[base + sub + 8];        // trip 1 (sub+8 <= 15, always valid)

    PV A, An;
    load_pv(pos, vel, idxA, A);

    float acc0 = 0.0f, acc1 = 0.0f, acc2 = 0.0f;

    for (int k = sub; k < cnt; k += LPP) {
        int idxC = nidx[base + min(k + 16, KMAX - 1)];   // trip i+2
        load_pv(pos, vel, idxB, An);                     // trip i+1
        pair_contrib(A, cpx, cpy, cpz, WsHP, acc0, acc1, acc2);
        idxB = idxC; A = An;
    }

    // reduce across the 8 lanes of this particle
    acc0 += __shfl_xor(acc0, 1); acc0 += __shfl_xor(acc0, 2); acc0 += __shfl_xor(acc0, 4);
    acc1 += __shfl_xor(acc1, 1); acc1 += __shfl_xor(acc1, 2); acc1 += __shfl_xor(acc1, 4);
    acc2 += __shfl_xor(acc2, 1); acc2 += __shfl_xor(acc2, 2); acc2 += __shfl_xor(acc2, 4);

    if (sub == 0) {
        out[p * 3 + 0] = acc0;
        out[p * 3 + 1] = acc1;
        out[p * 3 + 2] = acc2;
    }
}

extern "C" void kernel_launch(void* const* d_in, const int* in_sizes, int n_in,
                              void* d_out, int out_size, void* d_ws, size_t ws_size,
                              hipStream_t stream) {
    const float* pos   = (const float*)d_in[0];
    const float* vel   = (const float*)d_in[1];
    const float* Wg    = (const float*)d_in[2];
    const int*   nidx  = (const int*)d_in[3];
    const void*  nmask = d_in[4];
    float*       out   = (float*)d_out;

    int threads = 256;
    long long total = (long long)N_PART * LPP;   // 400K threads
    int grid = (int)((total + threads - 1) / threads);   // 1563
    cconv_kernel<<<grid, threads, 0, stream>>>(pos, vel, Wg, nidx, nmask, out);
}

// Round 15
// 29.141 us; speedup vs baseline: 1.1514x; 1.1514x over previous
//
#include <hip/hip_runtime.h>
#include <math.h>

#define N_PART 50000
#define KMAX 80
#define KS 4
#define LPP 16   // lanes per particle, slot stride = 16  (measured optimum)

typedef __attribute__((ext_vector_type(8))) _Float16 h8;
typedef __attribute__((ext_vector_type(2))) _Float16 h2;

// minimax odd polynomial for atan(t), t in [-1,1]; max abs err ~1e-5
__device__ __forceinline__ float atan_poly(float t) {
    float t2 = t * t;
    float p = -0.01172120f;
    p = p * t2 + 0.05265332f;
    p = p * t2 - 0.11643287f;
    p = p * t2 + 0.19354346f;
    p = p * t2 - 0.33262347f;
    p = p * t2 + 0.99997726f;
    return t * p;
}

// Count the true-prefix length of row p using this particle's 16 lanes.
template <typename MT>
__device__ __forceinline__ int prefix_count(const MT* __restrict__ nmask, int base, int sub) {
    int lc = 0; bool more = true;
    #pragma unroll
    for (int i = 0; i < 5; ++i) {
        bool t = nmask[base + sub * 5 + i] != 0;
        lc += (more && t) ? 1 : 0;
        more = more && t;
    }
    bool full = (lc == 5);
    unsigned long long nb = __ballot(!full);
    int wl  = threadIdx.x & 63;
    int grp = wl >> 4;
    unsigned int gb = (unsigned int)((nb >> (16 * grp)) & 0xFFFFull);
    if (gb == 0) return KMAX;
    int fi  = __ffs(gb) - 1;
    int flc = __shfl(lc, (grp << 4) + fi, 64);
    return fi * 5 + flc;
}

struct PV { float px, py, pz, ux, uy, uz; };

__device__ __forceinline__ void load_pv(const float* __restrict__ pos,
                                        const float* __restrict__ vel,
                                        int i, PV& v) {
    v.px = pos[3*i];  v.py = pos[3*i+1];  v.pz = pos[3*i+2];
    v.ux = vel[3*i];  v.uy = vel[3*i+1];  v.uz = vel[3*i+2];
}

// One (always-valid) pair's contribution: transform + corner fold.
__device__ __forceinline__ void pair_contrib(
    const PV& n, float cpx, float cpy, float cpz,
    const _Float16* __restrict__ WsH, const float* __restrict__ Ws8,
    float& acc0, float& acc1, float& acc2)
{
    const float inv_r = 1.0f / 0.3f;
    const float eps   = 1e-12f;
    const float FOUR_OVER_PI = 1.27323954473516268615f;

    float rx = (n.px - cpx) * inv_r;
    float ry = (n.py - cpy) * inv_r;
    float rz = (n.pz - cpz) * inv_r;

    float sq = rx * rx + ry * ry + rz * rz;

    // window_poly6: valid pairs have sq < 1, so no upper clamp needed
    float t1  = 1.0f - sq;
    float imp = fmaxf(t1 * t1 * t1, 0.0f);

    // ---- ball -> cylinder (volume preserving), branch-lite ----
    // eps-clamped math; the sq<eps / sq1<eps overrides are unreachable for
    // valid pairs (min inter-particle distance >> 1e-6) and match ref to 1e-6.
    float norm   = sqrtf(fmaxf(sq, eps));
    float sq_xy  = rx * rx + ry * ry;
    bool  top    = (1.25f * rz * rz) > sq_xy;
    float rsq_xy = __builtin_amdgcn_rsqf(fmaxf(sq_xy, eps));
    float s_top  = sqrtf(3.0f * norm * __builtin_amdgcn_rcpf(norm + fabsf(rz)));
    float z1 = top ? copysignf(norm, rz) : 1.5f * rz;

    // ---- cylinder -> cube ----
    // |y1|<=|x1| === |ry|<=|rx| (common positive scale s); ratio likewise.
    float nxy = top ? (sq_xy * rsq_xy * s_top) : norm;
    bool  xb  = fabsf(ry) <= fabsf(rx);
    float num = xb ? ry : rx;
    float den = xb ? rx : ry;
    float sden = (fabsf(den) > eps) ? den : 1.0f;
    float t    = num * __builtin_amdgcn_rcpf(sden);
    float at   = atan_poly(t);
    float sd   = copysignf(nxy, den);
    float u    = sd * FOUR_OVER_PI * at;
    float x2   = xb ? sd : u;
    float y2   = xb ? u  : sd;

    // ---- trilinear grid coords, align_corners=True, clamped ----
    float tx = fminf(fmaxf((x2 + 1.0f) * 1.5f, 0.0f), 3.0f);
    float ty = fminf(fmaxf((y2 + 1.0f) * 1.5f, 0.0f), 3.0f);
    float tz = fminf(fmaxf((z1 + 1.0f) * 1.5f, 0.0f), 3.0f);
    float fx0 = floorf(tx), fy0 = floorf(ty), fz0 = floorf(tz);
    int xi0 = (int)fx0, yi0 = (int)fy0, zi0 = (int)fz0;
    int xi1 = min(xi0 + 1, KS - 1);
    int yi1 = min(yi0 + 1, KS - 1);
    int zi1 = min(zi0 + 1, KS - 1);
    float wx1 = tx - fx0, wx0 = 1.0f - wx1;
    float wy1 = ty - fy0, wy0 = 1.0f - wy1;
    float wz1 = tz - fz0, wz0 = 1.0f - wz1;

    int   zia[2] = { zi0 << 4, zi1 << 4 };  float wza[2] = { wz0, wz1 };
    int   yia[2] = { yi0 << 2, yi1 << 2 };  float wya[2] = { wy0, wy1 };
    int   xia[2] = { xi0, xi1 };            float wxa[2] = { wx0, wx1 };

    // ---- per-pair M = sum_c w_c * W_c, accumulated in packed fp16 ----
    h2 M01 = (h2)(_Float16)0.0f;
    h2 M23 = (h2)(_Float16)0.0f;
    h2 M45 = (h2)(_Float16)0.0f;
    h2 M67 = (h2)(_Float16)0.0f;
    float m8 = 0.0f;

    #pragma unroll
    for (int cz = 0; cz < 2; ++cz) {
        #pragma unroll
        for (int cy = 0; cy < 2; ++cy) {
            float wzy = wza[cz] * wya[cy];
            int   czy = zia[cz] + yia[cy];
            #pragma unroll
            for (int cx = 0; cx < 2; ++cx) {
                int corner = czy + xia[cx];
                h8 wv = *(const h8*)&WsH[corner << 3];   // ds_read_b128
                float wf = wzy * wxa[cx];
                _Float16 wh = (_Float16)wf;
                h2 ww = { wh, wh };
                M01 += ww * __builtin_shufflevector(wv, wv, 0, 1);
                M23 += ww * __builtin_shufflevector(wv, wv, 2, 3);
                M45 += ww * __builtin_shufflevector(wv, wv, 4, 5);
                M67 += ww * __builtin_shufflevector(wv, wv, 6, 7);
                m8  += wf * Ws8[corner];                 // ds_read_b32
            }
        }
    }

    float m0 = (float)M01[0], m1 = (float)M01[1];
    float m2 = (float)M23[0], m3 = (float)M23[1];
    float m4 = (float)M45[0], m5 = (float)M45[1];
    float m6 = (float)M67[0], m7 = (float)M67[1];
    float s0 = n.ux * m0 + n.uy * m3 + n.uz * m6;
    float s1 = n.ux * m1 + n.uy * m4 + n.uz * m7;
    float s2 = n.ux * m2 + n.uy * m5 + n.uz * m8;
    acc0 += imp * s0;
    acc1 += imp * s1;
    acc2 += imp * s2;
}

__global__ __launch_bounds__(256) void cconv_kernel(
    const float* __restrict__ pos,
    const float* __restrict__ vel,
    const float* __restrict__ Wg,      // [64*3*3] (g, cin, cout)
    const int* __restrict__ nidx,      // [N][KMAX]
    const void* __restrict__ nmask,    // [N][KMAX], dtype detected per-wave
    float* __restrict__ out)           // [N][3]
{
    // W[c][0..7] as fp16 (one ds_read_b128/corner), W[c][8] as f32 (ds_read_b32).
    __shared__ _Float16 WsH[64 * 8];
    __shared__ float    Ws8[64];
    for (int t = threadIdx.x; t < 64 * 8; t += blockDim.x) {
        int g = t >> 3, r = t & 7;
        WsH[t] = (_Float16)Wg[g * 9 + r];
    }
    for (int t = threadIdx.x; t < 64; t += blockDim.x)
        Ws8[t] = Wg[t * 9 + 8];
    __syncthreads();

    int gid = blockIdx.x * blockDim.x + threadIdx.x;
    int p   = gid >> 4;        // 16 lanes per particle; grid exact
    int sub = gid & 15;
    if (p >= N_PART) return;

    const int base = p * KMAX;

    // ---- hoist ALL nidx loads for this lane (sub + m*16 <= 79 always) ----
    int idxs[5];
    #pragma unroll
    for (int m = 0; m < 5; ++m)
        idxs[m] = nidx[base + sub + (m << 4)];

    // ---- per-wave mask-dtype detection (int32 vs byte-bool storage) ----
    bool byteMask;
    {
        const unsigned* mw = (const unsigned*)nmask;
        int lane = threadIdx.x & 63;
        bool big = false;
        #pragma unroll
        for (int i = 0; i < 8; ++i)
            big |= (mw[lane + 64 * i] > 1u);
        byteMask = (__ballot(big) != 0ULL);
    }

    float cpx = pos[3 * p], cpy = pos[3 * p + 1], cpz = pos[3 * p + 2];

    int cnt;
    if (byteMask) cnt = prefix_count<unsigned char>((const unsigned char*)nmask, base, sub);
    else          cnt = prefix_count<int>((const int*)nmask, base, sub);

    // single-slot stride-16 loop: every executed slot is valid (exact exec-mask
    // tails), prefetch next slot's PV one iteration ahead.
    PV A, An;
    load_pv(pos, vel, idxs[0], A);

    float acc0 = 0.0f, acc1 = 0.0f, acc2 = 0.0f;

    int m = 0;
    for (int k = sub; k < cnt; k += LPP) {
        int mn = min(m + 1, 4);
        load_pv(pos, vel, idxs[mn], An);

        pair_contrib(A, cpx, cpy, cpz, WsH, Ws8, acc0, acc1, acc2);

        A = An; ++m;
    }

    // reduce across the 16 lanes of this particle
    acc0 += __shfl_xor(acc0, 1); acc0 += __shfl_xor(acc0, 2);
    acc0 += __shfl_xor(acc0, 4); acc0 += __shfl_xor(acc0, 8);
    acc1 += __shfl_xor(acc1, 1); acc1 += __shfl_xor(acc1, 2);
    acc1 += __shfl_xor(acc1, 4); acc1 += __shfl_xor(acc1, 8);
    acc2 += __shfl_xor(acc2, 1); acc2 += __shfl_xor(acc2, 2);
    acc2 += __shfl_xor(acc2, 4); acc2 += __shfl_xor(acc2, 8);

    if (sub == 0) {
        out[p * 3 + 0] = acc0;
        out[p * 3 + 1] = acc1;
        out[p * 3 + 2] = acc2;
    }
}

extern "C" void kernel_launch(void* const* d_in, const int* in_sizes, int n_in,
                              void* d_out, int out_size, void* d_ws, size_t ws_size,
                              hipStream_t stream) {
    const float* pos   = (const float*)d_in[0];
    const float* vel   = (const float*)d_in[1];
    const float* Wg    = (const float*)d_in[2];
    const int*   nidx  = (const int*)d_in[3];
    const void*  nmask = d_in[4];
    float*       out   = (float*)d_out;

    int threads = 256;
    long long total = (long long)N_PART * LPP;
    int grid = (int)((total + threads - 1) / threads);
    cconv_kernel<<<grid, threads, 0, stream>>>(pos, vel, Wg, nidx, nmask, out);
}